// Round 1
// baseline (345.066 us; speedup 1.0000x reference)
//
#include <hip/hip_runtime.h>
#include <math.h>

#define B 8
#define T 128
#define I_TOK 196
#define TEXT_DIM 768
#define IMAGE_DIM 1024
#define HIDDEN 512

// ---------------- Projection: Y[M,512] = X[M,K] @ W[K,512] + bias ----------
// 8 rows per block, 256 threads, each thread owns 2 output columns.
template<int K>
__global__ __launch_bounds__(256) void proj_kernel(const float* __restrict__ X,
        const float* __restrict__ W, const float* __restrict__ bias,
        float* __restrict__ Y)
{
    __shared__ float xs[8 * K];
    const int tid = threadIdx.x;
    const int m0 = blockIdx.x * 8;

    #pragma unroll
    for (int r = 0; r < 8; ++r)
        for (int d = tid; d < K; d += 256)
            xs[r * K + d] = X[(m0 + r) * K + d];
    __syncthreads();

    const int n0 = tid, n1 = tid + 256;
    float acc0[8], acc1[8];
    #pragma unroll
    for (int r = 0; r < 8; ++r) { acc0[r] = 0.f; acc1[r] = 0.f; }

    for (int d = 0; d < K; ++d) {
        const float w0 = W[d * HIDDEN + n0];
        const float w1 = W[d * HIDDEN + n1];
        #pragma unroll
        for (int r = 0; r < 8; ++r) {
            const float x = xs[r * K + d];
            acc0[r] = fmaf(x, w0, acc0[r]);
            acc1[r] = fmaf(x, w1, acc1[r]);
        }
    }
    const float b0 = bias[n0], b1 = bias[n1];
    #pragma unroll
    for (int r = 0; r < 8; ++r) {
        Y[(m0 + r) * HIDDEN + n0] = acc0[r] + b0;
        Y[(m0 + r) * HIDDEN + n1] = acc1[r] + b1;
    }
}

// ---------------- Scores: s[b,t,i] = wa . tanh(pt[b,t,:] + pi[b,i,:]) + ba --
__device__ __forceinline__ float fast_tanh(float x) {
    const float e = __expf(2.0f * x);
    return 1.0f - __fdividef(2.0f, e + 1.0f);
}

__global__ __launch_bounds__(256) void scores_kernel(const float* __restrict__ pt,
        const float* __restrict__ pi, const float* __restrict__ wa,
        const float* __restrict__ ba, float* __restrict__ scores)
{
    const int bt = blockIdx.x;          // b*T + t
    const int b = bt / T;
    const int tid = threadIdx.x;
    const int lane = tid & 63, wave = tid >> 6;

    const float* ptrow = pt + (long)bt * HIDDEN;
    float preg[8], wreg[8];
    #pragma unroll
    for (int k = 0; k < 8; ++k) {
        const int h = lane + k * 64;
        preg[k] = ptrow[h];
        wreg[k] = wa[h];
    }
    const float ba0 = ba[0];

    for (int i = wave; i < I_TOK; i += 4) {
        const float* prow = pi + ((long)b * I_TOK + i) * HIDDEN;
        float acc = 0.f;
        #pragma unroll
        for (int k = 0; k < 8; ++k) {
            const float th = fast_tanh(preg[k] + prow[lane + k * 64]);
            acc = fmaf(wreg[k], th, acc);
        }
        #pragma unroll
        for (int off = 32; off; off >>= 1)
            acc += __shfl_down(acc, off);
        if (lane == 0)
            scores[(long)bt * I_TOK + i] = acc + ba0;
    }
}

// ---------------- text_attended: softmax over i, weighted sum of image rows -
__global__ __launch_bounds__(256) void text_att_kernel(const float* __restrict__ scores,
        const float* __restrict__ image, float* __restrict__ out)
{
    const int bt = blockIdx.x;          // b*T + t
    const int b = bt / T;
    const int tid = threadIdx.x;
    const int lane = tid & 63, wave = tid >> 6;

    __shared__ float p[I_TOK];
    __shared__ float red[4];

    const float s = (tid < I_TOK) ? scores[(long)bt * I_TOK + tid] : -INFINITY;

    float m = s;
    #pragma unroll
    for (int off = 32; off; off >>= 1) m = fmaxf(m, __shfl_down(m, off));
    if (lane == 0) red[wave] = m;
    __syncthreads();
    m = fmaxf(fmaxf(red[0], red[1]), fmaxf(red[2], red[3]));

    const float e = (tid < I_TOK) ? __expf(s - m) : 0.f;
    float sum = e;
    #pragma unroll
    for (int off = 32; off; off >>= 1) sum += __shfl_down(sum, off);
    __syncthreads();
    if (lane == 0) red[wave] = sum;
    __syncthreads();
    sum = red[0] + red[1] + red[2] + red[3];
    const float inv = __fdividef(1.0f, sum);
    if (tid < I_TOK) p[tid] = e * inv;
    __syncthreads();

    const float* img = image + (long)b * I_TOK * IMAGE_DIM;
    float acc[4] = {0.f, 0.f, 0.f, 0.f};
    for (int i = 0; i < I_TOK; ++i) {
        const float pw = p[i];
        #pragma unroll
        for (int c = 0; c < 4; ++c)
            acc[c] = fmaf(pw, img[i * IMAGE_DIM + tid + c * 256], acc[c]);
    }
    #pragma unroll
    for (int c = 0; c < 4; ++c)
        out[(long)bt * IMAGE_DIM + tid + c * 256] = acc[c];
}

// ---------------- image_attended: softmax over t, weighted sum of text rows -
__global__ __launch_bounds__(256) void image_att_kernel(const float* __restrict__ scores,
        const float* __restrict__ text, float* __restrict__ out)
{
    const int bi = blockIdx.x;          // b*I_TOK + i
    const int b = bi / I_TOK;
    const int i = bi % I_TOK;
    const int tid = threadIdx.x;
    const int lane = tid & 63, wave = tid >> 6;

    __shared__ float q[T];
    __shared__ float red[4];

    const float s = (tid < T) ? scores[((long)b * T + tid) * I_TOK + i] : -INFINITY;

    float m = s;
    #pragma unroll
    for (int off = 32; off; off >>= 1) m = fmaxf(m, __shfl_down(m, off));
    if (lane == 0) red[wave] = m;
    __syncthreads();
    m = fmaxf(fmaxf(red[0], red[1]), fmaxf(red[2], red[3]));

    const float e = (tid < T) ? __expf(s - m) : 0.f;
    float sum = e;
    #pragma unroll
    for (int off = 32; off; off >>= 1) sum += __shfl_down(sum, off);
    __syncthreads();
    if (lane == 0) red[wave] = sum;
    __syncthreads();
    sum = red[0] + red[1] + red[2] + red[3];
    const float inv = __fdividef(1.0f, sum);
    if (tid < T) q[tid] = e * inv;
    __syncthreads();

    const float* txt = text + (long)b * T * TEXT_DIM;
    float acc[3] = {0.f, 0.f, 0.f};
    for (int t = 0; t < T; ++t) {
        const float qw = q[t];
        #pragma unroll
        for (int c = 0; c < 3; ++c)
            acc[c] = fmaf(qw, txt[t * TEXT_DIM + tid + c * 256], acc[c]);
    }
    #pragma unroll
    for (int c = 0; c < 3; ++c)
        out[(long)bi * TEXT_DIM + tid + c * 256] = acc[c];
}

extern "C" void kernel_launch(void* const* d_in, const int* in_sizes, int n_in,
                              void* d_out, int out_size, void* d_ws, size_t ws_size,
                              hipStream_t stream) {
    const float* text  = (const float*)d_in[0];
    const float* image = (const float*)d_in[1];
    const float* Wt    = (const float*)d_in[2];
    const float* bt    = (const float*)d_in[3];
    const float* Wi    = (const float*)d_in[4];
    const float* bi    = (const float*)d_in[5];
    const float* wa    = (const float*)d_in[6];
    const float* ba    = (const float*)d_in[7];

    float* pt = (float*)d_ws;                       // B*T*HIDDEN
    float* pi = pt + (long)B * T * HIDDEN;          // B*I*HIDDEN
    float* sc = pi + (long)B * I_TOK * HIDDEN;      // B*T*I

    float* out_text = (float*)d_out;                        // B*T*IMAGE_DIM
    float* out_img  = out_text + (long)B * T * IMAGE_DIM;   // B*I*TEXT_DIM

    proj_kernel<TEXT_DIM><<<B * T / 8, 256, 0, stream>>>(text, Wt, bt, pt);
    proj_kernel<IMAGE_DIM><<<B * I_TOK / 8, 256, 0, stream>>>(image, Wi, bi, pi);
    scores_kernel<<<B * T, 256, 0, stream>>>(pt, pi, wa, ba, sc);
    text_att_kernel<<<B * T, 256, 0, stream>>>(sc, image, out_text);
    image_att_kernel<<<B * I_TOK, 256, 0, stream>>>(sc, text, out_img);
}

// Round 2
// 288.137 us; speedup vs baseline: 1.1976x; 1.1976x over previous
//
#include <hip/hip_runtime.h>
#include <math.h>

#define B 8
#define T 128
#define I_TOK 196
#define TEXT_DIM 768
#define IMAGE_DIM 1024
#define HIDDEN 512

// ---------------- Fused projections --------------------------------------
// Text:  1024 rows x K=768  -> 128 row-tiles x 2 col-tiles = 256 blocks
// Image: 1568 rows x K=1024 -> 196 row-tiles x 2 col-tiles = 392 blocks
// Block: 256 threads, 8 rows x 256 cols. Thread owns 1 col, 8 rows.
// X-row values are block-uniform -> scalar loads; W reads coalesced.
#define TEXT_BLOCKS (2 * (B * T / 8))

__global__ __launch_bounds__(256) void proj_fused_kernel(
        const float* __restrict__ text, const float* __restrict__ Wt,
        const float* __restrict__ bt, const float* __restrict__ image,
        const float* __restrict__ Wi, const float* __restrict__ bi,
        float* __restrict__ pt, float* __restrict__ pi)
{
    const int bid = blockIdx.x;
    const int tid = threadIdx.x;

    const float* X; const float* W; const float* bias; float* Y;
    int K, m0, n0;
    if (bid < TEXT_BLOCKS) {
        X = text; W = Wt; bias = bt; Y = pt; K = TEXT_DIM;
        m0 = (bid >> 1) * 8; n0 = (bid & 1) * 256;
    } else {
        const int b2 = bid - TEXT_BLOCKS;
        X = image; W = Wi; bias = bi; Y = pi; K = IMAGE_DIM;
        m0 = (b2 >> 1) * 8; n0 = (b2 & 1) * 256;
    }

    const int n = n0 + tid;
    const float* Wp = W + n;
    const float* x0 = X + (long)m0 * K;

    float acc[8] = {0.f,0.f,0.f,0.f,0.f,0.f,0.f,0.f};

    for (int d = 0; d < K; d += 4) {
        const float w0 = Wp[(long)(d + 0) * HIDDEN];
        const float w1 = Wp[(long)(d + 1) * HIDDEN];
        const float w2 = Wp[(long)(d + 2) * HIDDEN];
        const float w3 = Wp[(long)(d + 3) * HIDDEN];
        #pragma unroll
        for (int r = 0; r < 8; ++r) {
            const float* xr = x0 + r * K + d;
            acc[r] = fmaf(xr[0], w0, acc[r]);
            acc[r] = fmaf(xr[1], w1, acc[r]);
            acc[r] = fmaf(xr[2], w2, acc[r]);
            acc[r] = fmaf(xr[3], w3, acc[r]);
        }
    }
    const float bv = bias[n];
    #pragma unroll
    for (int r = 0; r < 8; ++r)
        Y[(long)(m0 + r) * HIDDEN + n] = acc[r] + bv;
}

// ---------------- Scores: s[b,t,i] = wa . tanh(pt[b,t,:] + pi[b,i,:]) + ba
__device__ __forceinline__ float fast_tanh(float x) {
    const float e = __expf(2.0f * x);
    return 1.0f - __fdividef(2.0f, e + 1.0f);
}

__global__ __launch_bounds__(256) void scores_kernel(const float* __restrict__ pt,
        const float* __restrict__ pi, const float* __restrict__ wa,
        const float* __restrict__ ba, float* __restrict__ scores)
{
    const int bt = blockIdx.x;          // b*T + t
    const int b = bt / T;
    const int tid = threadIdx.x;
    const int lane = tid & 63, wave = tid >> 6;

    const float* ptrow = pt + (long)bt * HIDDEN;
    float preg[8], wreg[8];
    #pragma unroll
    for (int k = 0; k < 8; ++k) {
        const int h = lane + k * 64;
        preg[k] = ptrow[h];
        wreg[k] = wa[h];
    }
    const float ba0 = ba[0];

    for (int i = wave; i < I_TOK; i += 4) {
        const float* prow = pi + ((long)b * I_TOK + i) * HIDDEN;
        float acc = 0.f;
        #pragma unroll
        for (int k = 0; k < 8; ++k) {
            const float th = fast_tanh(preg[k] + prow[lane + k * 64]);
            acc = fmaf(wreg[k], th, acc);
        }
        #pragma unroll
        for (int off = 32; off; off >>= 1)
            acc += __shfl_down(acc, off);
        if (lane == 0)
            scores[(long)bt * I_TOK + i] = acc + ba0;
    }
}

// ---------------- text_attended: 4 t-rows + col-split 2 per block ---------
// grid = B * (T/4) * 2 = 512 blocks
__global__ __launch_bounds__(256) void text_att_kernel(const float* __restrict__ scores,
        const float* __restrict__ image, float* __restrict__ out)
{
    const int bid = blockIdx.x;
    const int csplit = bid & 1;
    const int grp = bid >> 1;           // 0..255
    const int b = grp >> 5;             // 32 t-groups per b
    const int t0 = (grp & 31) * 4;
    const int tid = threadIdx.x, lane = tid & 63, wave = tid >> 6;

    __shared__ float p[4][I_TOK];

    // per-wave softmax of score row t0+wave (196 entries over 64 lanes)
    {
        const float* srow = scores + ((long)(b * T + t0 + wave)) * I_TOK;
        const float s0 = srow[lane];
        const float s1 = srow[lane + 64];
        const float s2 = srow[lane + 128];
        const float s3 = (lane < 4) ? srow[lane + 192] : -INFINITY;
        float m = fmaxf(fmaxf(s0, s1), fmaxf(s2, s3));
        #pragma unroll
        for (int off = 32; off; off >>= 1) m = fmaxf(m, __shfl_xor(m, off));
        const float e0 = __expf(s0 - m);
        const float e1 = __expf(s1 - m);
        const float e2 = __expf(s2 - m);
        const float e3 = (lane < 4) ? __expf(s3 - m) : 0.f;
        float sum = e0 + e1 + e2 + e3;
        #pragma unroll
        for (int off = 32; off; off >>= 1) sum += __shfl_xor(sum, off);
        const float inv = __fdividef(1.0f, sum);
        p[wave][lane] = e0 * inv;
        p[wave][lane + 64] = e1 * inv;
        p[wave][lane + 128] = e2 * inv;
        if (lane < 4) p[wave][lane + 192] = e3 * inv;
    }
    __syncthreads();

    const float* img = image + (long)b * I_TOK * IMAGE_DIM + csplit * 512;
    float a00 = 0.f, a01 = 0.f, a10 = 0.f, a11 = 0.f;
    float a20 = 0.f, a21 = 0.f, a30 = 0.f, a31 = 0.f;
    for (int i = 0; i < I_TOK; ++i) {
        const float v0 = img[(long)i * IMAGE_DIM + tid];
        const float v1 = img[(long)i * IMAGE_DIM + tid + 256];
        const float p0 = p[0][i], p1 = p[1][i], p2 = p[2][i], p3 = p[3][i];
        a00 = fmaf(p0, v0, a00); a01 = fmaf(p0, v1, a01);
        a10 = fmaf(p1, v0, a10); a11 = fmaf(p1, v1, a11);
        a20 = fmaf(p2, v0, a20); a21 = fmaf(p2, v1, a21);
        a30 = fmaf(p3, v0, a30); a31 = fmaf(p3, v1, a31);
    }
    float* o = out + ((long)(b * T + t0)) * IMAGE_DIM + csplit * 512;
    o[0 * IMAGE_DIM + tid] = a00; o[0 * IMAGE_DIM + tid + 256] = a01;
    o[1 * IMAGE_DIM + tid] = a10; o[1 * IMAGE_DIM + tid + 256] = a11;
    o[2 * IMAGE_DIM + tid] = a20; o[2 * IMAGE_DIM + tid + 256] = a21;
    o[3 * IMAGE_DIM + tid] = a30; o[3 * IMAGE_DIM + tid + 256] = a31;
}

// ---------------- image_attended: 4 i-rows per block ----------------------
// grid = B * (I_TOK/4) = 392 blocks; thread owns 3 cols (768/256)
__global__ __launch_bounds__(256) void image_att_kernel(const float* __restrict__ scores,
        const float* __restrict__ text, float* __restrict__ out)
{
    const int bid = blockIdx.x;
    const int b = bid / (I_TOK / 4);    // 49 groups per b
    const int i0 = (bid % (I_TOK / 4)) * 4;
    const int tid = threadIdx.x, lane = tid & 63, wave = tid >> 6;

    __shared__ float q[4][T];

    // per-wave softmax over t (column i0+wave of the score matrix)
    {
        const float* sc = scores + (long)b * T * I_TOK + (i0 + wave);
        const float s0 = sc[(long)lane * I_TOK];
        const float s1 = sc[(long)(lane + 64) * I_TOK];
        float m = fmaxf(s0, s1);
        #pragma unroll
        for (int off = 32; off; off >>= 1) m = fmaxf(m, __shfl_xor(m, off));
        const float e0 = __expf(s0 - m);
        const float e1 = __expf(s1 - m);
        float sum = e0 + e1;
        #pragma unroll
        for (int off = 32; off; off >>= 1) sum += __shfl_xor(sum, off);
        const float inv = __fdividef(1.0f, sum);
        q[wave][lane] = e0 * inv;
        q[wave][lane + 64] = e1 * inv;
    }
    __syncthreads();

    const float* txt = text + (long)b * T * TEXT_DIM;
    float a00=0.f,a01=0.f,a02=0.f, a10=0.f,a11=0.f,a12=0.f;
    float a20=0.f,a21=0.f,a22=0.f, a30=0.f,a31=0.f,a32=0.f;
    for (int t = 0; t < T; ++t) {
        const float v0 = txt[(long)t * TEXT_DIM + tid];
        const float v1 = txt[(long)t * TEXT_DIM + tid + 256];
        const float v2 = txt[(long)t * TEXT_DIM + tid + 512];
        const float q0 = q[0][t], q1 = q[1][t], q2 = q[2][t], q3 = q[3][t];
        a00 = fmaf(q0, v0, a00); a01 = fmaf(q0, v1, a01); a02 = fmaf(q0, v2, a02);
        a10 = fmaf(q1, v0, a10); a11 = fmaf(q1, v1, a11); a12 = fmaf(q1, v2, a12);
        a20 = fmaf(q2, v0, a20); a21 = fmaf(q2, v1, a21); a22 = fmaf(q2, v2, a22);
        a30 = fmaf(q3, v0, a30); a31 = fmaf(q3, v1, a31); a32 = fmaf(q3, v2, a32);
    }
    float* o = out + ((long)b * I_TOK + i0) * TEXT_DIM;
    o[0 * TEXT_DIM + tid] = a00; o[0 * TEXT_DIM + tid + 256] = a01; o[0 * TEXT_DIM + tid + 512] = a02;
    o[1 * TEXT_DIM + tid] = a10; o[1 * TEXT_DIM + tid + 256] = a11; o[1 * TEXT_DIM + tid + 512] = a12;
    o[2 * TEXT_DIM + tid] = a20; o[2 * TEXT_DIM + tid + 256] = a21; o[2 * TEXT_DIM + tid + 512] = a22;
    o[3 * TEXT_DIM + tid] = a30; o[3 * TEXT_DIM + tid + 256] = a31; o[3 * TEXT_DIM + tid + 512] = a32;
}

extern "C" void kernel_launch(void* const* d_in, const int* in_sizes, int n_in,
                              void* d_out, int out_size, void* d_ws, size_t ws_size,
                              hipStream_t stream) {
    const float* text  = (const float*)d_in[0];
    const float* image = (const float*)d_in[1];
    const float* Wt    = (const float*)d_in[2];
    const float* bt    = (const float*)d_in[3];
    const float* Wi    = (const float*)d_in[4];
    const float* bi    = (const float*)d_in[5];
    const float* wa    = (const float*)d_in[6];
    const float* ba    = (const float*)d_in[7];

    float* pt = (float*)d_ws;                       // B*T*HIDDEN
    float* pi = pt + (long)B * T * HIDDEN;          // B*I*HIDDEN
    float* sc = pi + (long)B * I_TOK * HIDDEN;      // B*T*I

    float* out_text = (float*)d_out;                        // B*T*IMAGE_DIM
    float* out_img  = out_text + (long)B * T * IMAGE_DIM;   // B*I*TEXT_DIM

    const int proj_blocks = TEXT_BLOCKS + 2 * (B * I_TOK / 8);   // 256 + 392
    proj_fused_kernel<<<proj_blocks, 256, 0, stream>>>(text, Wt, bt, image, Wi, bi, pt, pi);
    scores_kernel<<<B * T, 256, 0, stream>>>(pt, pi, wa, ba, sc);
    text_att_kernel<<<B * (T / 4) * 2, 256, 0, stream>>>(sc, image, out_text);
    image_att_kernel<<<B * (I_TOK / 4), 256, 0, stream>>>(sc, text, out_img);
}

// Round 3
// 202.193 us; speedup vs baseline: 1.7066x; 1.4251x over previous
//
#include <hip/hip_runtime.h>
#include <math.h>

#define B 8
#define T 128
#define I_TOK 196
#define TEXT_DIM 768
#define IMAGE_DIM 1024
#define HIDDEN 512

// ---------------- Fused projections v3 ------------------------------------
// 4 rows per block, all 512 cols. 256 threads = 2 K-halves x 128 col-groups
// (4 cols each). X staged transposed in LDS so one ds_read_b128 = 4 rows at
// one d (same-address broadcast across the half -> conflict-free). W read as
// float4 (coalesced 1KB/wave). K-halves combined through LDS at the end.
#define TEXT_TILES (B * T / 4)        // 256
#define IMG_TILES  (B * I_TOK / 4)    // 392

__global__ __launch_bounds__(256) void proj_kernel(
        const float* __restrict__ text, const float* __restrict__ Wt,
        const float* __restrict__ bt, const float* __restrict__ image,
        const float* __restrict__ Wi, const float* __restrict__ bi,
        float* __restrict__ pt, float* __restrict__ pi)
{
    __shared__ float xs[IMAGE_DIM * 4];   // 16 KB (transposed X tile)
    __shared__ float part[4 * HIDDEN];    // 8 KB (upper-K partial sums)

    const int bid = blockIdx.x;
    const int tid = threadIdx.x;

    const float* X; const float* W; const float* bias; float* Y;
    int K, m0;
    if (bid < TEXT_TILES) {
        X = text; W = Wt; bias = bt; Y = pt; K = TEXT_DIM; m0 = bid * 4;
    } else {
        X = image; W = Wi; bias = bi; Y = pi; K = IMAGE_DIM;
        m0 = (bid - TEXT_TILES) * 4;
    }

    // stage X[m0..m0+3][*] transposed -> xs[d*4 + r]
    for (int d = tid; d < K; d += 256) {
        float4 v;
        v.x = X[(long)(m0 + 0) * K + d];
        v.y = X[(long)(m0 + 1) * K + d];
        v.z = X[(long)(m0 + 2) * K + d];
        v.w = X[(long)(m0 + 3) * K + d];
        *(float4*)&xs[d * 4] = v;
    }
    __syncthreads();

    const int kh = tid >> 7;          // which K-half
    const int cg = tid & 127;         // col group
    const int n  = cg * 4;
    const int Kh = K >> 1;

    float4 acc0 = {0,0,0,0}, acc1 = {0,0,0,0}, acc2 = {0,0,0,0}, acc3 = {0,0,0,0};

    const float* Wp = W + (long)kh * Kh * HIDDEN + n;
    const float* xp = xs + (long)kh * Kh * 4;

#define PSTEP(xv, wv) \
    acc0.x = fmaf(xv.x, wv.x, acc0.x); acc0.y = fmaf(xv.x, wv.y, acc0.y); \
    acc0.z = fmaf(xv.x, wv.z, acc0.z); acc0.w = fmaf(xv.x, wv.w, acc0.w); \
    acc1.x = fmaf(xv.y, wv.x, acc1.x); acc1.y = fmaf(xv.y, wv.y, acc1.y); \
    acc1.z = fmaf(xv.y, wv.z, acc1.z); acc1.w = fmaf(xv.y, wv.w, acc1.w); \
    acc2.x = fmaf(xv.z, wv.x, acc2.x); acc2.y = fmaf(xv.z, wv.y, acc2.y); \
    acc2.z = fmaf(xv.z, wv.z, acc2.z); acc2.w = fmaf(xv.z, wv.w, acc2.w); \
    acc3.x = fmaf(xv.w, wv.x, acc3.x); acc3.y = fmaf(xv.w, wv.y, acc3.y); \
    acc3.z = fmaf(xv.w, wv.z, acc3.z); acc3.w = fmaf(xv.w, wv.w, acc3.w);

    for (int d = 0; d < Kh; d += 4) {
        const float4 w0 = *(const float4*)(Wp + (long)(d + 0) * HIDDEN);
        const float4 w1 = *(const float4*)(Wp + (long)(d + 1) * HIDDEN);
        const float4 w2 = *(const float4*)(Wp + (long)(d + 2) * HIDDEN);
        const float4 w3 = *(const float4*)(Wp + (long)(d + 3) * HIDDEN);
        const float4 x0 = *(const float4*)(xp + (d + 0) * 4);
        const float4 x1 = *(const float4*)(xp + (d + 1) * 4);
        const float4 x2 = *(const float4*)(xp + (d + 2) * 4);
        const float4 x3 = *(const float4*)(xp + (d + 3) * 4);
        PSTEP(x0, w0) PSTEP(x1, w1) PSTEP(x2, w2) PSTEP(x3, w3)
    }

    if (kh == 1) {
        *(float4*)&part[0 * HIDDEN + n] = acc0;
        *(float4*)&part[1 * HIDDEN + n] = acc1;
        *(float4*)&part[2 * HIDDEN + n] = acc2;
        *(float4*)&part[3 * HIDDEN + n] = acc3;
    }
    __syncthreads();
    if (kh == 0) {
        const float4 bv = *(const float4*)(bias + n);
        const float4 p0 = *(const float4*)&part[0 * HIDDEN + n];
        const float4 p1 = *(const float4*)&part[1 * HIDDEN + n];
        const float4 p2 = *(const float4*)&part[2 * HIDDEN + n];
        const float4 p3 = *(const float4*)&part[3 * HIDDEN + n];
        float4 o;
        o.x = acc0.x + p0.x + bv.x; o.y = acc0.y + p0.y + bv.y;
        o.z = acc0.z + p0.z + bv.z; o.w = acc0.w + p0.w + bv.w;
        *(float4*)(Y + (long)(m0 + 0) * HIDDEN + n) = o;
        o.x = acc1.x + p1.x + bv.x; o.y = acc1.y + p1.y + bv.y;
        o.z = acc1.z + p1.z + bv.z; o.w = acc1.w + p1.w + bv.w;
        *(float4*)(Y + (long)(m0 + 1) * HIDDEN + n) = o;
        o.x = acc2.x + p2.x + bv.x; o.y = acc2.y + p2.y + bv.y;
        o.z = acc2.z + p2.z + bv.z; o.w = acc2.w + p2.w + bv.w;
        *(float4*)(Y + (long)(m0 + 2) * HIDDEN + n) = o;
        o.x = acc3.x + p3.x + bv.x; o.y = acc3.y + p3.y + bv.y;
        o.z = acc3.z + p3.z + bv.z; o.w = acc3.w + p3.w + bv.w;
        *(float4*)(Y + (long)(m0 + 3) * HIDDEN + n) = o;
    }
}

// ---------------- Scores: s[b,t,i] = wa . tanh(pt[b,t,:] + pi[b,i,:]) + ba
__device__ __forceinline__ float fast_tanh(float x) {
    const float e = __expf(2.0f * x);
    return 1.0f - __fdividef(2.0f, e + 1.0f);
}

__global__ __launch_bounds__(256) void scores_kernel(const float* __restrict__ pt,
        const float* __restrict__ pi, const float* __restrict__ wa,
        const float* __restrict__ ba, float* __restrict__ scores)
{
    const int bt = blockIdx.x;          // b*T + t
    const int b = bt / T;
    const int tid = threadIdx.x;
    const int lane = tid & 63, wave = tid >> 6;

    const float* ptrow = pt + (long)bt * HIDDEN;
    float preg[8], wreg[8];
    #pragma unroll
    for (int k = 0; k < 8; ++k) {
        const int h = lane + k * 64;
        preg[k] = ptrow[h];
        wreg[k] = wa[h];
    }
    const float ba0 = ba[0];

    for (int i = wave; i < I_TOK; i += 4) {
        const float* prow = pi + ((long)b * I_TOK + i) * HIDDEN;
        float acc = 0.f;
        #pragma unroll
        for (int k = 0; k < 8; ++k) {
            const float th = fast_tanh(preg[k] + prow[lane + k * 64]);
            acc = fmaf(wreg[k], th, acc);
        }
        #pragma unroll
        for (int off = 32; off; off >>= 1)
            acc += __shfl_down(acc, off);
        if (lane == 0)
            scores[(long)bt * I_TOK + i] = acc + ba0;
    }
}

// ---------------- Fused attended outputs ----------------------------------
// blocks [0,512): text_attended (4 t-rows, col-half per block)
// blocks [512,904): image_attended (4 i-rows per block)
__global__ __launch_bounds__(256) void att_kernel(const float* __restrict__ scores,
        const float* __restrict__ image, const float* __restrict__ text,
        float* __restrict__ out_text, float* __restrict__ out_img)
{
    const int tid = threadIdx.x, lane = tid & 63, wave = tid >> 6;

    if (blockIdx.x < 512) {
        const int bid = blockIdx.x;
        const int csplit = bid & 1;
        const int grp = bid >> 1;           // 0..255
        const int b = grp >> 5;
        const int t0 = (grp & 31) * 4;

        __shared__ float p[4][I_TOK];
        {
            const float* srow = scores + ((long)(b * T + t0 + wave)) * I_TOK;
            const float s0 = srow[lane];
            const float s1 = srow[lane + 64];
            const float s2 = srow[lane + 128];
            const float s3 = (lane < 4) ? srow[lane + 192] : -INFINITY;
            float m = fmaxf(fmaxf(s0, s1), fmaxf(s2, s3));
            #pragma unroll
            for (int off = 32; off; off >>= 1) m = fmaxf(m, __shfl_xor(m, off));
            const float e0 = __expf(s0 - m);
            const float e1 = __expf(s1 - m);
            const float e2 = __expf(s2 - m);
            const float e3 = (lane < 4) ? __expf(s3 - m) : 0.f;
            float sum = e0 + e1 + e2 + e3;
            #pragma unroll
            for (int off = 32; off; off >>= 1) sum += __shfl_xor(sum, off);
            const float inv = __fdividef(1.0f, sum);
            p[wave][lane] = e0 * inv;
            p[wave][lane + 64] = e1 * inv;
            p[wave][lane + 128] = e2 * inv;
            if (lane < 4) p[wave][lane + 192] = e3 * inv;
        }
        __syncthreads();

        const float* img = image + (long)b * I_TOK * IMAGE_DIM + csplit * 512;
        float a00 = 0.f, a01 = 0.f, a10 = 0.f, a11 = 0.f;
        float a20 = 0.f, a21 = 0.f, a30 = 0.f, a31 = 0.f;
        for (int i = 0; i < I_TOK; ++i) {
            const float v0 = img[(long)i * IMAGE_DIM + tid];
            const float v1 = img[(long)i * IMAGE_DIM + tid + 256];
            const float p0 = p[0][i], p1 = p[1][i], p2 = p[2][i], p3 = p[3][i];
            a00 = fmaf(p0, v0, a00); a01 = fmaf(p0, v1, a01);
            a10 = fmaf(p1, v0, a10); a11 = fmaf(p1, v1, a11);
            a20 = fmaf(p2, v0, a20); a21 = fmaf(p2, v1, a21);
            a30 = fmaf(p3, v0, a30); a31 = fmaf(p3, v1, a31);
        }
        float* o = out_text + ((long)(b * T + t0)) * IMAGE_DIM + csplit * 512;
        o[0 * IMAGE_DIM + tid] = a00; o[0 * IMAGE_DIM + tid + 256] = a01;
        o[1 * IMAGE_DIM + tid] = a10; o[1 * IMAGE_DIM + tid + 256] = a11;
        o[2 * IMAGE_DIM + tid] = a20; o[2 * IMAGE_DIM + tid + 256] = a21;
        o[3 * IMAGE_DIM + tid] = a30; o[3 * IMAGE_DIM + tid + 256] = a31;
    } else {
        const int bid = blockIdx.x - 512;
        const int b = bid / (I_TOK / 4);
        const int i0 = (bid % (I_TOK / 4)) * 4;

        __shared__ float q[4][T];
        {
            const float* sc = scores + (long)b * T * I_TOK + (i0 + wave);
            const float s0 = sc[(long)lane * I_TOK];
            const float s1 = sc[(long)(lane + 64) * I_TOK];
            float m = fmaxf(s0, s1);
            #pragma unroll
            for (int off = 32; off; off >>= 1) m = fmaxf(m, __shfl_xor(m, off));
            const float e0 = __expf(s0 - m);
            const float e1 = __expf(s1 - m);
            float sum = e0 + e1;
            #pragma unroll
            for (int off = 32; off; off >>= 1) sum += __shfl_xor(sum, off);
            const float inv = __fdividef(1.0f, sum);
            q[wave][lane] = e0 * inv;
            q[wave][lane + 64] = e1 * inv;
        }
        __syncthreads();

        const float* txt = text + (long)b * T * TEXT_DIM;
        float a00=0.f,a01=0.f,a02=0.f, a10=0.f,a11=0.f,a12=0.f;
        float a20=0.f,a21=0.f,a22=0.f, a30=0.f,a31=0.f,a32=0.f;
        for (int t = 0; t < T; ++t) {
            const float v0 = txt[(long)t * TEXT_DIM + tid];
            const float v1 = txt[(long)t * TEXT_DIM + tid + 256];
            const float v2 = txt[(long)t * TEXT_DIM + tid + 512];
            const float q0 = q[0][t], q1 = q[1][t], q2 = q[2][t], q3 = q[3][t];
            a00 = fmaf(q0, v0, a00); a01 = fmaf(q0, v1, a01); a02 = fmaf(q0, v2, a02);
            a10 = fmaf(q1, v0, a10); a11 = fmaf(q1, v1, a11); a12 = fmaf(q1, v2, a12);
            a20 = fmaf(q2, v0, a20); a21 = fmaf(q2, v1, a21); a22 = fmaf(q2, v2, a22);
            a30 = fmaf(q3, v0, a30); a31 = fmaf(q3, v1, a31); a32 = fmaf(q3, v2, a32);
        }
        float* o = out_img + ((long)b * I_TOK + i0) * TEXT_DIM;
        o[0 * TEXT_DIM + tid] = a00; o[0 * TEXT_DIM + tid + 256] = a01; o[0 * TEXT_DIM + tid + 512] = a02;
        o[1 * TEXT_DIM + tid] = a10; o[1 * TEXT_DIM + tid + 256] = a11; o[1 * TEXT_DIM + tid + 512] = a12;
        o[2 * TEXT_DIM + tid] = a20; o[2 * TEXT_DIM + tid + 256] = a21; o[2 * TEXT_DIM + tid + 512] = a22;
        o[3 * TEXT_DIM + tid] = a30; o[3 * TEXT_DIM + tid + 256] = a31; o[3 * TEXT_DIM + tid + 512] = a32;
    }
}

extern "C" void kernel_launch(void* const* d_in, const int* in_sizes, int n_in,
                              void* d_out, int out_size, void* d_ws, size_t ws_size,
                              hipStream_t stream) {
    const float* text  = (const float*)d_in[0];
    const float* image = (const float*)d_in[1];
    const float* Wt    = (const float*)d_in[2];
    const float* bt    = (const float*)d_in[3];
    const float* Wi    = (const float*)d_in[4];
    const float* bi    = (const float*)d_in[5];
    const float* wa    = (const float*)d_in[6];
    const float* ba    = (const float*)d_in[7];

    float* pt = (float*)d_ws;                       // B*T*HIDDEN
    float* pi = pt + (long)B * T * HIDDEN;          // B*I*HIDDEN
    float* sc = pi + (long)B * I_TOK * HIDDEN;      // B*T*I

    float* out_text = (float*)d_out;                        // B*T*IMAGE_DIM
    float* out_img  = out_text + (long)B * T * IMAGE_DIM;   // B*I*TEXT_DIM

    proj_kernel<<<TEXT_TILES + IMG_TILES, 256, 0, stream>>>(text, Wt, bt, image, Wi, bi, pt, pi);
    scores_kernel<<<B * T, 256, 0, stream>>>(pt, pi, wa, ba, sc);
    att_kernel<<<512 + B * (I_TOK / 4), 256, 0, stream>>>(sc, image, text, out_text, out_img);
}